// Round 1
// baseline (1106.687 us; speedup 1.0000x reference)
//
#include <hip/hip_runtime.h>

// Problem: VOCAB=32000, H=1024, L=256, B=64.  Only batch row 0 matters
// (reference broadcasts hs[:, :1, :]), so this is a single-sequence GRU.
#define SENT 0xAAAAAAAAu

__device__ __forceinline__ float sigf(float x) { return 1.0f / (1.0f + __expf(-x)); }
__device__ __forceinline__ float tanh_fast(float x) {
  float e = __expf(2.0f * x);
  return 1.0f - 2.0f / (e + 1.0f);
}

// ---------- K1 v2: gi[t][j] = emb[x[t][0]] . w_ih[j] + b_ih[j] (+ b_hh[j] for j<2048) ----------
// v1 had thread=t with per-lane emb rows -> every load was a 64-line scatter
// (~3 GB of L2 line traffic, address-divergence-bound, ~250 us).
// v2: block = 256 threads (thread = t), owns 12 j-rows (grid 256 = 1 block/CU,
// 3072 = 256*12). Per 32-k chunk: stage E[256][32] in LDS with k-coalesced
// loads (8 lanes x float4 per row), pad stride 33 -> conflict-free per-row
// reads; W stays wave-uniform (j0 per block) -> scalar s_loads, no vmem
// scatter. Chunk c+1 prefetched into regs during compute of chunk c.
__global__ __launch_bounds__(256) void k1_gi(const int* __restrict__ x,
                                             const float* __restrict__ emb,
                                             const float* __restrict__ w_ih,
                                             const float* __restrict__ b_ih,
                                             const float* __restrict__ b_hh,
                                             float* __restrict__ gi)
{
  __shared__ float elds[256 * 33];   // 33.8 KB, +1 pad word per row
  __shared__ int   idxs[256];

  const int tid = threadIdx.x;
  const int j0  = blockIdx.x * 12;

  idxs[tid] = x[tid * 64];           // x[t][0] (int32 data, row stride 64)
  __syncthreads();

  // 8 fixed staging rows per thread: r = p*32 + tid/8, cols (tid&7)*4 .. +3
  const float* base[8];
#pragma unroll
  for (int p = 0; p < 8; ++p)
    base[p] = emb + (size_t)idxs[p * 32 + (tid >> 3)] * 1024 + ((tid & 7) * 4);

  float acc[12];
#pragma unroll
  for (int j = 0; j < 12; ++j) {
    const int jj = j0 + j;
    acc[j] = b_ih[jj] + (jj < 2048 ? b_hh[jj] : 0.0f);  // fold b_hh for r,z gates
  }

  float4 st[8];
#pragma unroll
  for (int p = 0; p < 8; ++p) st[p] = *(const float4*)(base[p]);   // chunk 0

  for (int kc = 0; kc < 1024; kc += 32) {
    // staged regs -> LDS (write banks ~2-way max: (r + 4c + u) mod 32)
#pragma unroll
    for (int p = 0; p < 8; ++p) {
      const int r = p * 32 + (tid >> 3), c = (tid & 7) * 4;
      float* d = elds + r * 33 + c;
      d[0] = st[p].x; d[1] = st[p].y; d[2] = st[p].z; d[3] = st[p].w;
    }
    __syncthreads();

    // prefetch next chunk while computing this one (latency hidden under FMAs)
    if (kc < 992) {
#pragma unroll
      for (int p = 0; p < 8; ++p) st[p] = *(const float4*)(base[p] + kc + 32);
    }

    float e[32];
#pragma unroll
    for (int i = 0; i < 32; ++i) e[i] = elds[tid * 33 + i];  // own row, conflict-free

#pragma unroll
    for (int j = 0; j < 12; ++j) {
      const float* w = w_ih + (size_t)(j0 + j) * 1024 + kc;  // wave-uniform -> s_load
#pragma unroll
      for (int i = 0; i < 32; ++i) acc[j] = fmaf(e[i], w[i], acc[j]);
    }
    __syncthreads();   // reads of this chunk done before next chunk's LDS writes
  }

  float* g = gi + (size_t)tid * 3072 + j0;                   // j0 = 12b, 16B-aligned
  *(float4*)(g)     = make_float4(acc[0], acc[1], acc[2],  acc[3]);
  *(float4*)(g + 4) = make_float4(acc[4], acc[5], acc[6],  acc[7]);
  *(float4*)(g + 8) = make_float4(acc[8], acc[9], acc[10], acc[11]);
}

// ---------- K2: persistent recurrence (UNCHANGED from measured 733 us version) ----------
// grid 128 x 512 (8 waves). Wave wv of block g owns h element hj = 8g+wv; its three
// w_hh rows (r,z,n) live in 48 fp32 VGPRs per lane (no LDS weight traffic per step).
// Sync: sentinel-in-data. Producers (lane 0) store h bits with a relaxed agent atomic
// (sc0 sc1 -> L3 coherence point). Each wave polls only ITS 128-word chunk of h[t-1]
// with ONE coalesced u64 relaxed-agent atomic load per lane per round (always fresh at
// L3; no buffer_inv storm, gi/w_out scalar loads stay cached), then fills its hlds
// chunk in parallel. barrier1 = whole hlds valid; barrier2 (end of step) guards the
// WAR hazard chunk-fill(t+1) vs hlds-reads(t).
__global__ __launch_bounds__(512) void k2_rec(const float* __restrict__ w_hh,
                                              const float* __restrict__ b_hh,
                                              const float* __restrict__ gi,
                                              const float* __restrict__ w_out,
                                              unsigned int* __restrict__ hseq,
                                              float* __restrict__ acc)
{
  __shared__ float hlds[1024];   // 4 KB only

  const int g    = blockIdx.x;
  const int tid  = threadIdx.x;
  const int wv   = tid >> 6;
  const int lane = tid & 63;
  const int hj   = __builtin_amdgcn_readfirstlane(g * 8 + wv);  // uniform -> s_loads

  // ---- weights into VGPRs: w[gate*4+j] holds row[j*256 + lane*4 .. +3] ----
  float4 w[12];
#pragma unroll
  for (int gate = 0; gate < 3; ++gate) {
    const float* row = w_hh + (size_t)(gate * 1024 + hj) * 1024;
#pragma unroll
    for (int j = 0; j < 4; ++j)
      w[gate * 4 + j] = *(const float4*)(row + j * 256 + lane * 4);
  }
  const float bhh_n = b_hh[2048 + hj];
  float hp = 0.0f, wout_acc = 0.0f;

  const unsigned long long* hs64 = (const unsigned long long*)hseq;

#pragma unroll 1
  for (int t = 0; t < 256; ++t) {
    // wave-uniform scalar prefetches (overlap the poll round-trip)
    const float gi_r = gi[(size_t)t * 3072 + hj];
    const float gi_z = gi[(size_t)t * 3072 + 1024 + hj];
    const float gi_n = gi[(size_t)t * 3072 + 2048 + hj];
    const float wo   = w_out[(size_t)t * 1024 + hj];

    float ar = 0.f, az = 0.f, an = 0.f;

    if (t > 0) {
      // poll own 512 B chunk of row t-1: one u64 atomic load per lane per round
      const unsigned long long* p = hs64 + (size_t)(t - 1) * 512 + wv * 64 + lane;
      unsigned long long v;
      for (;;) {
        v = __hip_atomic_load(p, __ATOMIC_RELAXED, __HIP_MEMORY_SCOPE_AGENT);
        const bool ok = (((unsigned int)v) != SENT) &
                        (((unsigned int)(v >> 32)) != SENT);
        if (__all(ok)) break;
      }
      const int w0 = wv * 128 + lane * 2;          // 8B-aligned -> ds_write_b64
      hlds[w0]     = __uint_as_float((unsigned int)v);
      hlds[w0 + 1] = __uint_as_float((unsigned int)(v >> 32));
      __syncthreads();                              // barrier1: hlds fully valid

      // dot: lane owns k = j*256 + lane*4 + c
#pragma unroll
      for (int j = 0; j < 4; ++j) {
        const float4 h4 = *(const float4*)&hlds[j * 256 + lane * 4];
        const float4 wr = w[j], wz = w[4 + j], wn = w[8 + j];
        ar = fmaf(h4.x, wr.x, ar); ar = fmaf(h4.y, wr.y, ar);
        ar = fmaf(h4.z, wr.z, ar); ar = fmaf(h4.w, wr.w, ar);
        az = fmaf(h4.x, wz.x, az); az = fmaf(h4.y, wz.y, az);
        az = fmaf(h4.z, wz.z, az); az = fmaf(h4.w, wz.w, az);
        an = fmaf(h4.x, wn.x, an); an = fmaf(h4.y, wn.y, an);
        an = fmaf(h4.z, wn.z, an); an = fmaf(h4.w, wn.w, an);
      }
#pragma unroll
      for (int m = 1; m < 64; m <<= 1) {
        ar += __shfl_xor(ar, m, 64);
        az += __shfl_xor(az, m, 64);
        an += __shfl_xor(an, m, 64);
      }
    }

    const float r  = sigf(ar + gi_r);               // b_ih+b_hh folded into gi_r/gi_z
    const float z  = sigf(az + gi_z);
    const float n  = tanh_fast(gi_n + r * (an + bhh_n));
    const float h2 = (1.0f - z) * n + z * hp;

    unsigned int bits = __float_as_uint(h2);
    if (bits == SENT) bits ^= 1u;                   // never store the sentinel
    if (lane == 0) {
      __hip_atomic_store(hseq + (size_t)t * 1024 + hj, bits, __ATOMIC_RELAXED,
                         __HIP_MEMORY_SCOPE_AGENT);
      wout_acc = fmaf(__uint_as_float(bits), wo, wout_acc);  // fold w_out dot in
    }
    hp = __uint_as_float(bits);

    if (t > 0) __syncthreads();  // barrier2: hlds reads(t) done before fill(t+1)
  }

  if (lane == 0) atomicAdd(acc, wout_acc);
}

// ---------- K3: pure feat broadcast: feat[b][i] = hseq[i] for all 64 b ----------
__global__ __launch_bounds__(256) void k3_bcast(const float* __restrict__ hseq_f,
                                                float* __restrict__ outbuf)
{
  const int gtid = blockIdx.x * 256 + threadIdx.x;
  const float4* src = (const float4*)hseq_f;    // 65536 float4
  float4* dst = (float4*)outbuf;
  for (int q = gtid; q < 64 * 65536; q += 1024 * 256) {
    const int b = q >> 16, i4 = q & 65535;
    dst[(size_t)b * 65536 + i4] = src[i4];
  }
}

// ---------- K4: out[b] = sigmoid(acc + b_out) for all 64 b ----------
__global__ void k4_fin(const float* __restrict__ acc, const float* __restrict__ b_out,
                       float* __restrict__ outbuf)
{
  const float s = sigf(acc[0] + b_out[0]);
  outbuf[(size_t)16777216 + threadIdx.x] = s;
}

// ---------- launch ----------
extern "C" void kernel_launch(void* const* d_in, const int* in_sizes, int n_in,
                              void* d_out, int out_size, void* d_ws, size_t ws_size,
                              hipStream_t stream) {
  const int*   x     = (const int*)d_in[0];
  const float* emb   = (const float*)d_in[1];
  const float* w_ih  = (const float*)d_in[2];
  const float* w_hh  = (const float*)d_in[3];
  const float* b_ih  = (const float*)d_in[4];
  const float* b_hh  = (const float*)d_in[5];
  const float* w_out = (const float*)d_in[6];
  const float* b_out = (const float*)d_in[7];
  float* out = (float*)d_out;

  char* ws = (char*)d_ws;
  float*        gi   = (float*)ws;                       // 3,145,728 B
  unsigned int* hseq = (unsigned int*)(ws + 3145728);    // 1,048,576 B
  float*        acc  = (float*)(ws + 4194304);           // 4 B

  hipMemsetAsync(hseq, 0xAA, (size_t)256 * 1024 * 4, stream);  // sentinel init
  hipMemsetAsync(acc, 0, 4, stream);

  hipLaunchKernelGGL(k1_gi,    dim3(256),  dim3(256), 0, stream, x, emb, w_ih, b_ih, b_hh, gi);
  hipLaunchKernelGGL(k2_rec,   dim3(128),  dim3(512), 0, stream, w_hh, b_hh, gi, w_out, hseq, acc);
  hipLaunchKernelGGL(k3_bcast, dim3(1024), dim3(256), 0, stream, (const float*)hseq, out);
  hipLaunchKernelGGL(k4_fin,   dim3(1),    dim3(64),  0, stream, acc, b_out, out);
}

// Round 2
// 1016.506 us; speedup vs baseline: 1.0887x; 1.0887x over previous
//
#include <hip/hip_runtime.h>

// Problem: VOCAB=32000, H=1024, L=256, B=64.  Only batch row 0 matters
// (reference broadcasts hs[:, :1, :]), so this is a single-sequence GRU.
#define SENT 0xAAAAAAAAu

__device__ __forceinline__ float sigf(float x) { return 1.0f / (1.0f + __expf(-x)); }
__device__ __forceinline__ float tanh_fast(float x) {
  float e = __expf(2.0f * x);
  return 1.0f - 2.0f / (e + 1.0f);
}

// ---------- K1 (v1, reverted): gi[t][j] = emb[x[t][0]] . w_ih[j] + b_ih[j] (+ b_hh[j] for j<2048) ----------
// grid 768 blocks (4 j-rows each) x 256 thr (thread = t). 3 blocks/CU for latency hiding.
// NOTE (R1 post-mortem): LDS-staged variant with 1 block/CU was +78 us WORSE —
// the scattered emb reads are L2-resident (256 rows = 1 MB) and 12 waves/CU hide
// the latency. Keep v1.
__global__ __launch_bounds__(256) void k1_gi(const int* __restrict__ x,
                                             const float* __restrict__ emb,
                                             const float* __restrict__ w_ih,
                                             const float* __restrict__ b_ih,
                                             const float* __restrict__ b_hh,
                                             float* __restrict__ gi)
{
  const int j0 = blockIdx.x * 4;
  const int t  = threadIdx.x;
  const int idx = x[t * 64];                       // x[t][0]
  const float* er = emb + (size_t)idx * 1024;

  float acc[4];
#pragma unroll
  for (int j = 0; j < 4; ++j) {
    const int jj = j0 + j;
    acc[j] = b_ih[jj] + (jj < 2048 ? b_hh[jj] : 0.0f);  // fold b_hh for r,z gates
  }

  for (int kc = 0; kc < 1024; kc += 16) {
    const float4 e0 = *(const float4*)(er + kc);
    const float4 e1 = *(const float4*)(er + kc + 4);
    const float4 e2 = *(const float4*)(er + kc + 8);
    const float4 e3 = *(const float4*)(er + kc + 12);
    const float e[16] = {e0.x, e0.y, e0.z, e0.w, e1.x, e1.y, e1.z, e1.w,
                         e2.x, e2.y, e2.z, e2.w, e3.x, e3.y, e3.z, e3.w};
#pragma unroll
    for (int j = 0; j < 4; ++j) {
      const float* w = w_ih + (size_t)(j0 + j) * 1024 + kc;  // wave-uniform -> s_load
#pragma unroll
      for (int i = 0; i < 16; ++i) acc[j] = fmaf(e[i], w[i], acc[j]);
    }
  }
  *(float4*)(gi + (size_t)t * 3072 + j0) = make_float4(acc[0], acc[1], acc[2], acc[3]);
}

// ---------- K2: persistent recurrence ----------
// grid 128 x 512 (8 waves). Wave wv of block g owns h element hj = 8g+wv; its three
// w_hh rows (r,z,n) live in 48 fp32 VGPRs per lane (no LDS weight traffic per step).
// Sync: sentinel-in-data. Producers (lane 0) store h bits agent-scope (-> L3, the
// memory-side coherence point). R2 CHANGE: the poll is now a PLAIN wave-coalesced
// global_load_dwordx2 with sc0 sc1 (L2-bypass) instead of a per-lane u64 ATOMIC load.
// Atomics never coalesce: each poll round was 64 separate 8B atomic transactions per
// wave (65k/round device-wide) serializing in the L3 atomic path. Plain sc0sc1 loads
// coalesce to 8 line-requests/wave/round with identical freshness semantics (each
// dword is written exactly once: SENT -> final; L3 is memory-side and always
// coherent, sc1 forces the stale-L2 bypass).
__global__ __launch_bounds__(512) void k2_rec(const float* __restrict__ w_hh,
                                              const float* __restrict__ b_hh,
                                              const float* __restrict__ gi,
                                              const float* __restrict__ w_out,
                                              unsigned int* __restrict__ hseq,
                                              float* __restrict__ acc)
{
  __shared__ float hlds[1024];   // 4 KB only

  const int g    = blockIdx.x;
  const int tid  = threadIdx.x;
  const int wv   = tid >> 6;
  const int lane = tid & 63;
  const int hj   = __builtin_amdgcn_readfirstlane(g * 8 + wv);  // uniform -> s_loads

  // ---- weights into VGPRs: w[gate*4+j] holds row[j*256 + lane*4 .. +3] ----
  float4 w[12];
#pragma unroll
  for (int gate = 0; gate < 3; ++gate) {
    const float* row = w_hh + (size_t)(gate * 1024 + hj) * 1024;
#pragma unroll
    for (int j = 0; j < 4; ++j)
      w[gate * 4 + j] = *(const float4*)(row + j * 256 + lane * 4);
  }
  const float bhh_n = b_hh[2048 + hj];
  float hp = 0.0f, wout_acc = 0.0f;

  const unsigned long long* hs64 = (const unsigned long long*)hseq;

#pragma unroll 1
  for (int t = 0; t < 256; ++t) {
    // wave-uniform scalar prefetches (overlap the poll round-trip)
    const float gi_r = gi[(size_t)t * 3072 + hj];
    const float gi_z = gi[(size_t)t * 3072 + 1024 + hj];
    const float gi_n = gi[(size_t)t * 3072 + 2048 + hj];
    const float wo   = w_out[(size_t)t * 1024 + hj];

    float ar = 0.f, az = 0.f, an = 0.f;

    if (t > 0) {
      // poll own 512 B chunk of row t-1: one coalesced plain dwordx2 (sc0 sc1) per
      // lane per round. Fresh at L3 (memory-side, always coherent); sc1 bypasses
      // the possibly-stale XCD L2. Values are {SENT | final}, so no atomicity needed.
      const unsigned long long* p = hs64 + (size_t)(t - 1) * 512 + wv * 64 + lane;
      unsigned long long v;
      for (;;) {
        asm volatile("global_load_dwordx2 %0, %1, off sc0 sc1\n\t"
                     "s_waitcnt vmcnt(0)"
                     : "=v"(v) : "v"(p) : "memory");
        const bool ok = (((unsigned int)v) != SENT) &
                        (((unsigned int)(v >> 32)) != SENT);
        if (__all(ok)) break;
      }
      const int w0 = wv * 128 + lane * 2;          // 8B-aligned -> ds_write_b64
      hlds[w0]     = __uint_as_float((unsigned int)v);
      hlds[w0 + 1] = __uint_as_float((unsigned int)(v >> 32));
      __syncthreads();                              // barrier1: hlds fully valid

      // dot: lane owns k = j*256 + lane*4 + c
#pragma unroll
      for (int j = 0; j < 4; ++j) {
        const float4 h4 = *(const float4*)&hlds[j * 256 + lane * 4];
        const float4 wr = w[j], wz = w[4 + j], wn = w[8 + j];
        ar = fmaf(h4.x, wr.x, ar); ar = fmaf(h4.y, wr.y, ar);
        ar = fmaf(h4.z, wr.z, ar); ar = fmaf(h4.w, wr.w, ar);
        az = fmaf(h4.x, wz.x, az); az = fmaf(h4.y, wz.y, az);
        az = fmaf(h4.z, wz.z, az); az = fmaf(h4.w, wz.w, az);
        an = fmaf(h4.x, wn.x, an); an = fmaf(h4.y, wn.y, an);
        an = fmaf(h4.z, wn.z, an); an = fmaf(h4.w, wn.w, an);
      }
#pragma unroll
      for (int m = 1; m < 64; m <<= 1) {
        ar += __shfl_xor(ar, m, 64);
        az += __shfl_xor(az, m, 64);
        an += __shfl_xor(an, m, 64);
      }
    }

    const float r  = sigf(ar + gi_r);               // b_ih+b_hh folded into gi_r/gi_z
    const float z  = sigf(az + gi_z);
    const float n  = tanh_fast(gi_n + r * (an + bhh_n));
    const float h2 = (1.0f - z) * n + z * hp;

    unsigned int bits = __float_as_uint(h2);
    if (bits == SENT) bits ^= 1u;                   // never store the sentinel
    if (lane == 0) {
      __hip_atomic_store(hseq + (size_t)t * 1024 + hj, bits, __ATOMIC_RELAXED,
                         __HIP_MEMORY_SCOPE_AGENT);
      wout_acc = fmaf(__uint_as_float(bits), wo, wout_acc);  // fold w_out dot in
    }
    hp = __uint_as_float(bits);

    if (t > 0) __syncthreads();  // barrier2: hlds reads(t) done before fill(t+1)
  }

  if (lane == 0) atomicAdd(acc, wout_acc);
}

// ---------- K3: pure feat broadcast: feat[b][i] = hseq[i] for all 64 b ----------
__global__ __launch_bounds__(256) void k3_bcast(const float* __restrict__ hseq_f,
                                                float* __restrict__ outbuf)
{
  const int gtid = blockIdx.x * 256 + threadIdx.x;
  const float4* src = (const float4*)hseq_f;    // 65536 float4
  float4* dst = (float4*)outbuf;
  for (int q = gtid; q < 64 * 65536; q += 1024 * 256) {
    const int b = q >> 16, i4 = q & 65535;
    dst[(size_t)b * 65536 + i4] = src[i4];
  }
}

// ---------- K4: out[b] = sigmoid(acc + b_out) for all 64 b ----------
__global__ void k4_fin(const float* __restrict__ acc, const float* __restrict__ b_out,
                       float* __restrict__ outbuf)
{
  const float s = sigf(acc[0] + b_out[0]);
  outbuf[(size_t)16777216 + threadIdx.x] = s;
}

// ---------- launch ----------
extern "C" void kernel_launch(void* const* d_in, const int* in_sizes, int n_in,
                              void* d_out, int out_size, void* d_ws, size_t ws_size,
                              hipStream_t stream) {
  const int*   x     = (const int*)d_in[0];
  const float* emb   = (const float*)d_in[1];
  const float* w_ih  = (const float*)d_in[2];
  const float* w_hh  = (const float*)d_in[3];
  const float* b_ih  = (const float*)d_in[4];
  const float* b_hh  = (const float*)d_in[5];
  const float* w_out = (const float*)d_in[6];
  const float* b_out = (const float*)d_in[7];
  float* out = (float*)d_out;

  char* ws = (char*)d_ws;
  float*        gi   = (float*)ws;                       // 3,145,728 B
  unsigned int* hseq = (unsigned int*)(ws + 3145728);    // 1,048,576 B
  float*        acc  = (float*)(ws + 4194304);           // 4 B

  hipMemsetAsync(hseq, 0xAA, (size_t)256 * 1024 * 4, stream);  // sentinel init
  hipMemsetAsync(acc, 0, 4, stream);

  hipLaunchKernelGGL(k1_gi,    dim3(768),  dim3(256), 0, stream, x, emb, w_ih, b_ih, b_hh, gi);
  hipLaunchKernelGGL(k2_rec,   dim3(128),  dim3(512), 0, stream, w_hh, b_hh, gi, w_out, hseq, acc);
  hipLaunchKernelGGL(k3_bcast, dim3(1024), dim3(256), 0, stream, (const float*)hseq, out);
  hipLaunchKernelGGL(k4_fin,   dim3(1),    dim3(64),  0, stream, acc, b_out, out);
}